// Round 4
// baseline (708.088 us; speedup 1.0000x reference)
//
#include <hip/hip_runtime.h>

// Problem constants
#define TOK 4096      // B*S tokens
#define DD  1024      // model dim
#define NE  8         // experts
#define FF  4096      // ffn dim
#define NB  8         // batch
#define SS  512       // seq
#define HROWS 8320    // 8192 token-pairs + per-expert tile padding

typedef unsigned short ushort_t;
typedef __attribute__((ext_vector_type(8))) short bshort8;   // 8 bf16 = 4 VGPRs
typedef __attribute__((ext_vector_type(4))) float floatx4;   // MFMA C/D

__device__ __forceinline__ ushort_t f2bf(float f) {
  unsigned int u = __float_as_uint(f);
  u += 0x7fffu + ((u >> 16) & 1u);
  return (ushort_t)(u >> 16);
}
__device__ __forceinline__ float bf2f(ushort_t h) {
  return __uint_as_float(((unsigned int)h) << 16);
}

// async 16B global->LDS (LDS dest = wave-uniform base + lane*16)
__device__ __forceinline__ void gl_lds16(const ushort_t* g, ushort_t* l) {
  __builtin_amdgcn_global_load_lds(
      (const __attribute__((address_space(1))) unsigned int*)g,
      (__attribute__((address_space(3))) unsigned int*)l, 16, 0, 0);
}

// ---------------------------------------------------------------------------
// fp32 -> bf16 cast
// ---------------------------------------------------------------------------
__global__ __launch_bounds__(256) void k_cast(
    const float* __restrict__ in, ushort_t* __restrict__ out, int n4) {
  int i = blockIdx.x * 256 + threadIdx.x;
  if (i < n4) {
    float4 v = ((const float4*)in)[i];
    ushort4 o;
    o.x = f2bf(v.x); o.y = f2bf(v.y); o.z = f2bf(v.z); o.w = f2bf(v.w);
    ((ushort4*)out)[i] = o;
  }
}

// ---------------------------------------------------------------------------
// Transpose + cast: out[c][r] = bf16(in[r][c]); 64x64 tiles.
// fp32 LDS [64][65] -> conflict-free (bank = (r + c) % 32), ushort4 stores.
// ---------------------------------------------------------------------------
__global__ __launch_bounds__(256) void k_transpose_cast(
    const float* __restrict__ in, size_t in_estride, int in_rstride,
    ushort_t* __restrict__ out, size_t out_estride, int out_rstride) {
  __shared__ float t[64][65];
  const float* ib = in + blockIdx.z * in_estride;
  ushort_t* ob = out + blockIdx.z * out_estride;
  const int r0 = blockIdx.y * 64, c0 = blockIdx.x * 64;
  const int tid = threadIdx.x;
  const int lr = tid >> 4, lc4 = (tid & 15) * 4;
#pragma unroll
  for (int it = 0; it < 4; ++it) {
    int r = lr + it * 16;
    float4 v = *(const float4*)&ib[(size_t)(r0 + r) * in_rstride + c0 + lc4];
    t[r][lc4 + 0] = v.x; t[r][lc4 + 1] = v.y;
    t[r][lc4 + 2] = v.z; t[r][lc4 + 3] = v.w;
  }
  __syncthreads();
  const int od4 = (tid & 15) * 4, oc = tid >> 4;
#pragma unroll
  for (int it = 0; it < 4; ++it) {
    int cc = oc + it * 16;
    ushort4 w;
    w.x = f2bf(t[od4 + 0][cc]);
    w.y = f2bf(t[od4 + 1][cc]);
    w.z = f2bf(t[od4 + 2][cc]);
    w.w = f2bf(t[od4 + 3][cc]);
    *(ushort4*)&ob[(size_t)(c0 + cc) * out_rstride + r0 + od4] = w;
  }
}

// ---------------------------------------------------------------------------
// MFMA GEMM, 128x128 tile, BK=64 (full 128B lines), bf16 in, fp32 acc.
//   kext: K extent (= B row stride), ast: A row stride, ost: MODE1 out stride
//   nsplit/klen: split-K (blockIdx.z = e*nsplit + s; k in [s*klen, s*klen+klen))
// MODE 0: lin = A @ B^T + bias              -> bf16 Obf rows m0+m, stride DD
// MODE 1: h   = relu(A[gather] @ B^T + b1)  -> bf16 Obf rows off+p, stride ost
// MODE 2: ob += A @ B^T  (atomicAdd; ob pre-zeroed, b2 added in pool)
// ---------------------------------------------------------------------------
template <int MODE>
__global__ __launch_bounds__(256) void k_mfma(
    const ushort_t* __restrict__ A, const ushort_t* __restrict__ Bm,
    const float* __restrict__ bias, ushort_t* __restrict__ Obf,
    float* __restrict__ Of, const int* __restrict__ cnt,
    const int* __restrict__ offs, const int* __restrict__ btok, int f0,
    int kext, int ast, int ost, size_t bstride, int nsplit, int klen) {
  int e = 0, sp = 0;
  if (MODE != 0) { e = blockIdx.z / nsplit; sp = blockIdx.z % nsplit; }
  int c = TOK, off = 0;
  if (MODE != 0) {
    c = cnt[e];
    off = offs[e];
    if ((int)blockIdx.y * 128 >= c) return;
  }
  const int m0 = blockIdx.y * 128;
  const int n0 = blockIdx.x * 128;
  const ushort_t* Bp = (MODE == 0) ? Bm : Bm + (size_t)e * bstride;
  const int kbeg = sp * klen, kfin = kbeg + klen;

  __shared__ ushort_t Als[128 * 64];
  __shared__ ushort_t Bls[128 * 64];
  __shared__ int ts[128];

  const int tid = threadIdx.x;
  if (tid < 128) {
    int p = m0 + tid;
    int r;
    if (MODE == 0) r = p;
    else if (MODE == 1) r = btok[e * TOK + min(p, c - 1)];
    else r = off + p;
    ts[tid] = r;
  }

  const int lane = tid & 63;
  const int w = tid >> 6;
  const int wm = (w & 1) * 64, wn = (w >> 1) * 64;
  const int lm = lane & 15, lq = lane >> 4;
  const int sr = lane >> 3;   // row within 8-row staging group
  const int sg = lane & 7;    // 16B group within 128B row

  floatx4 zero = {0.f, 0.f, 0.f, 0.f};
  floatx4 acc[4][4];
#pragma unroll
  for (int i = 0; i < 4; ++i)
#pragma unroll
    for (int j = 0; j < 4; ++j) acc[i][j] = zero;

  for (int k0 = kbeg; k0 < kfin; k0 += 64) {
    __syncthreads();  // prev frag reads done; ts[] visible (iter 0)
#pragma unroll
    for (int i = 0; i < 4; ++i) {
      int r = w * 32 + i * 8 + sr;
      int q = (sg - r) & 7;  // XOR-swizzle on the global side
      gl_lds16(A + (size_t)ts[r] * ast + k0 + q * 8, Als + r * 64 + sg * 8);
    }
#pragma unroll
    for (int i = 0; i < 4; ++i) {
      int r = w * 32 + i * 8 + sr;
      int q = (sg - r) & 7;
      gl_lds16(Bp + (size_t)(n0 + r) * kext + k0 + q * 8,
               Bls + r * 64 + sg * 8);
    }
    __syncthreads();  // drain global_load_lds

#pragma unroll
    for (int kh = 0; kh < 2; ++kh) {
      bshort8 af[4], bfr[4];
#pragma unroll
      for (int i = 0; i < 4; ++i) {
        int r = wm + i * 16 + lm;
        af[i] = *(const bshort8*)&Als[r * 64 + (((kh * 4 + lq + r) & 7) * 8)];
      }
#pragma unroll
      for (int j = 0; j < 4; ++j) {
        int r = wn + j * 16 + lm;
        bfr[j] = *(const bshort8*)&Bls[r * 64 + (((kh * 4 + lq + r) & 7) * 8)];
      }
#pragma unroll
      for (int i = 0; i < 4; ++i)
#pragma unroll
        for (int j = 0; j < 4; ++j)
          acc[i][j] = __builtin_amdgcn_mfma_f32_16x16x32_bf16(
              af[i], bfr[j], acc[i][j], 0, 0, 0);
    }
  }

  // epilogue: C mapping col = lane&15, row = (lane>>4)*4 + reg  [m89-verified]
#pragma unroll
  for (int i = 0; i < 4; ++i) {
#pragma unroll
    for (int j = 0; j < 4; ++j) {
      int n = wn + j * 16 + lm;
#pragma unroll
      for (int rr = 0; rr < 4; ++rr) {
        int m = wm + i * 16 + lq * 4 + rr;
        float v = acc[i][j][rr];
        if (MODE == 0) {
          int gn = n0 + n;
          v += bias[gn];
          Obf[(size_t)(m0 + m) * DD + gn] = f2bf(v);
        } else if (MODE == 1) {
          int p = m0 + m;
          if (p < c) {
            int gn = n0 + n;
            v += bias[(size_t)e * FF + f0 + gn];
            v = fmaxf(v, 0.f);
            Obf[(size_t)(off + p) * ost + gn] = f2bf(v);
          }
        } else {
          int p = m0 + m;
          if (p < c) {
            atomicAdd(&Of[(size_t)(off + p) * DD + n0 + n], v);
          }
        }
      }
    }
  }
}

// ---------------------------------------------------------------------------
// Phase 1 gate: logits + top-2 + renormalized weights. No atomics.
// ---------------------------------------------------------------------------
__global__ __launch_bounds__(256) void k_logits(
    const ushort_t* __restrict__ lin_bf, const float* __restrict__ Wg,
    int* __restrict__ topi, float* __restrict__ wts) {
  const int wv = threadIdx.x >> 6, lane = threadIdx.x & 63;
  const int t = blockIdx.x * 4 + wv;
  float acc[NE] = {};
  const ushort_t* lr = lin_bf + (size_t)t * DD;
#pragma unroll 4
  for (int d0 = 0; d0 < DD; d0 += 64) {
    float v = bf2f(lr[d0 + lane]);
    const float* wgr = Wg + (size_t)(d0 + lane) * NE;
    float4 g0 = *(const float4*)(wgr);
    float4 g1 = *(const float4*)(wgr + 4);
    acc[0] += v * g0.x; acc[1] += v * g0.y; acc[2] += v * g0.z; acc[3] += v * g0.w;
    acc[4] += v * g1.x; acc[5] += v * g1.y; acc[6] += v * g1.z; acc[7] += v * g1.w;
  }
#pragma unroll
  for (int off = 32; off > 0; off >>= 1) {
#pragma unroll
    for (int e = 0; e < NE; ++e) acc[e] += __shfl_xor(acc[e], off);
  }
  if (lane == 0) {
    int i1 = 0;
#pragma unroll
    for (int e = 1; e < NE; ++e)
      if (acc[e] > acc[i1]) i1 = e;
    int i2 = (i1 == 0) ? 1 : 0;
#pragma unroll
    for (int e = 0; e < NE; ++e)
      if (e != i1 && acc[e] > acc[i2]) i2 = e;
    float r = __expf(acc[i2] - acc[i1]);
    topi[t] = i1 | (i2 << 4);
    wts[2 * t + 0] = 1.0f / (1.0f + r);
    wts[2 * t + 1] = r / (1.0f + r);
  }
}

// ---------------------------------------------------------------------------
// Phase 2 route: single block, deterministic counting-sort
// ---------------------------------------------------------------------------
#define RT 512
__global__ __launch_bounds__(RT) void k_route(
    const int* __restrict__ topi, int* __restrict__ cnt, int* __restrict__ offs,
    int* __restrict__ btok, int* __restrict__ eslot) {
  __shared__ int sc[NE][RT + 1];
  __shared__ int tot[NE];
  const int tid = threadIdx.x;
  int lc[NE] = {};
  int my[8];
#pragma unroll
  for (int i = 0; i < 8; ++i) {
    int t = tid * 8 + i;
    int p = topi[t];
    my[i] = p;
    lc[p & 15]++;
    lc[(p >> 4) & 15]++;
  }
#pragma unroll
  for (int e = 0; e < NE; ++e) sc[e][tid] = lc[e];
  __syncthreads();
  if (tid < NE) {
    int s = 0;
    for (int i = 0; i < RT; ++i) { int v = sc[tid][i]; sc[tid][i] = s; s += v; }
    tot[tid] = s;
  }
  __syncthreads();
  if (tid == 0) {
    int s = 0;
    for (int e = 0; e < NE; ++e) { offs[e] = s; cnt[e] = tot[e]; s += tot[e]; }
  }
  __syncthreads();
  int run[NE];
#pragma unroll
  for (int e = 0; e < NE; ++e) run[e] = sc[e][tid];
#pragma unroll
  for (int i = 0; i < 8; ++i) {
    int t = tid * 8 + i, p = my[i];
    int e1 = p & 15, e2 = (p >> 4) & 15;
    int s1 = run[e1]++;
    btok[e1 * TOK + s1] = t;
    eslot[2 * t + 0] = e1 * TOK + s1;
    int s2 = run[e2]++;
    btok[e2 * TOK + s2] = t;
    eslot[2 * t + 1] = e2 * TOK + s2;
  }
}

// ---------------------------------------------------------------------------
// Pool: sent[b][d] = (1/S)*sum_s( x + w0*(ob[g0]+b2[e0]) + w1*(ob[g1]+b2[e1]) )
// ---------------------------------------------------------------------------
__global__ __launch_bounds__(256) void k_pool(
    const float* __restrict__ x, const float* __restrict__ ob,
    const float* __restrict__ b2, const int* __restrict__ offs,
    const int* __restrict__ eslot, const float* __restrict__ wts,
    float* __restrict__ sent) {
  const int b = blockIdx.y;
  const int d = blockIdx.x * 256 + threadIdx.x;
  const int sc = blockIdx.z;
  float a = 0.f;
  for (int s = sc * 64; s < sc * 64 + 64; ++s) {
    int t = b * SS + s;
    int e0 = eslot[2 * t], e1 = eslot[2 * t + 1];
    int x0 = e0 >> 12, x1 = e1 >> 12;
    int g0 = offs[x0] + (e0 & (TOK - 1));
    int g1 = offs[x1] + (e1 & (TOK - 1));
    a += x[(size_t)t * DD + d] +
         wts[2 * t + 0] * (ob[(size_t)g0 * DD + d] + b2[x0 * DD + d]) +
         wts[2 * t + 1] * (ob[(size_t)g1 * DD + d] + b2[x1 * DD + d]);
  }
  atomicAdd(&sent[b * DD + d], a * (1.0f / SS));
}

// ---------------------------------------------------------------------------
// Loss
// ---------------------------------------------------------------------------
__global__ __launch_bounds__(1024) void k_loss(
    const float* __restrict__ sent, const int* __restrict__ y,
    float* __restrict__ out) {
  __shared__ float red[16];
  const int tid = threadIdx.x;
  const int lane = tid & 63, wv = tid >> 6;
  float loss = 0.f;
  for (int b = 0; b < NB; ++b) {
    float v = sent[b * DD + tid];
    float m = v;
#pragma unroll
    for (int off = 32; off > 0; off >>= 1) m = fmaxf(m, __shfl_xor(m, off));
    if (lane == 0) red[wv] = m;
    __syncthreads();
    float m2 = red[0];
#pragma unroll
    for (int w = 1; w < 16; ++w) m2 = fmaxf(m2, red[w]);
    __syncthreads();
    float ex = __expf(v - m2);
#pragma unroll
    for (int off = 32; off > 0; off >>= 1) ex += __shfl_xor(ex, off);
    if (lane == 0) red[wv] = ex;
    __syncthreads();
    if (tid == 0) {
      float se = 0.f;
      for (int w = 0; w < 16; ++w) se += red[w];
      loss += m2 + logf(se) - sent[b * DD + y[b]];
    }
    __syncthreads();
  }
  if (tid == 0) out[0] = loss / NB;
}

// ---------------------------------------------------------------------------
extern "C" void kernel_launch(void* const* d_in, const int* in_sizes, int n_in,
                              void* d_out, int out_size, void* d_ws,
                              size_t ws_size, hipStream_t stream) {
  const float* x  = (const float*)d_in[0];
  const int*   y  = (const int*)d_in[1];
  const float* W  = (const float*)d_in[2];
  const float* bb = (const float*)d_in[3];
  const float* Wg = (const float*)d_in[4];
  const float* w1 = (const float*)d_in[5];
  const float* b1 = (const float*)d_in[6];
  const float* w2 = (const float*)d_in[7];
  const float* b2 = (const float*)d_in[8];
  float* out = (float*)d_out;

  auto need = [](size_t FCr) -> size_t {
    size_t o = 0;
    auto al = [&](size_t b) { o = (o + b + 255) & ~255ull; };
    al((size_t)TOK * DD * 2);           // lin_bf
    al((size_t)TOK * DD * 2);           // x_bf
    al((size_t)DD * DD * 2);            // W_bf
    al((size_t)HROWS * FCr * 2);        // h_bf
    al((size_t)NE * FCr * DD * 2);      // w1t
    al((size_t)NE * DD * FCr * 2);      // w2t
    al((size_t)HROWS * DD * 4);         // ob
    al((size_t)NE * TOK * 4);           // btok
    al(64); al(64);                     // cnt, offs
    al((size_t)TOK * 4);                // topi
    al((size_t)2 * TOK * 4);            // eslot
    al((size_t)2 * TOK * 4);            // wts
    al((size_t)NB * DD * 4);            // sent
    return o;
  };
  const int nchunks = (ws_size >= need(FF)) ? 1 : 4;
  const int FCr = FF / nchunks;
  const int nsplit = (nchunks == 1) ? 4 : 1;  // split-K for mode2

  char* base = (char*)d_ws;
  size_t o = 0;
  auto al = [&](size_t b) -> char* {
    char* p = base + o;
    o = (o + b + 255) & ~255ull;
    return p;
  };
  ushort_t* lin_bf = (ushort_t*)al((size_t)TOK * DD * 2);
  ushort_t* x_bf   = (ushort_t*)al((size_t)TOK * DD * 2);
  ushort_t* W_bf   = (ushort_t*)al((size_t)DD * DD * 2);
  ushort_t* h_bf   = (ushort_t*)al((size_t)HROWS * FCr * 2);
  ushort_t* w1t    = (ushort_t*)al((size_t)NE * FCr * DD * 2);
  ushort_t* w2t    = (ushort_t*)al((size_t)NE * DD * FCr * 2);
  float*    ob     = (float*)al((size_t)HROWS * DD * 4);
  int*      btok   = (int*)al((size_t)NE * TOK * 4);
  int*      cnt    = (int*)al(64);
  int*      offs   = (int*)al(64);
  int*      topi   = (int*)al((size_t)TOK * 4);
  int*      eslot  = (int*)al((size_t)2 * TOK * 4);
  float*    wts    = (float*)al((size_t)2 * TOK * 4);
  float*    sent   = (float*)al((size_t)NB * DD * 4);

  hipMemsetAsync(sent, 0, NB * DD * sizeof(float), stream);
  hipMemsetAsync(ob, 0, (size_t)HROWS * DD * 4, stream);  // mode2 atomic target

  k_cast<<<TOK * DD / 4 / 256, 256, 0, stream>>>(x, x_bf, TOK * DD / 4);
  k_cast<<<DD * DD / 4 / 256, 256, 0, stream>>>(W, W_bf, DD * DD / 4);

  // lin = x @ W^T + b
  k_mfma<0><<<dim3(DD / 128, TOK / 128), 256, 0, stream>>>(
      x_bf, W_bf, bb, lin_bf, nullptr, nullptr, nullptr, nullptr, 0,
      DD, DD, DD, 0, 1, DD);

  // gate + deterministic routing
  k_logits<<<TOK / 4, 256, 0, stream>>>(lin_bf, Wg, topi, wts);
  k_route<<<1, RT, 0, stream>>>(topi, cnt, offs, btok, eslot);

  // expert FFN
  for (int ci = 0; ci < nchunks; ++ci) {
    int f0 = ci * FCr;
    // w1[:, :, f0:f0+FCr] -> w1t [e][f][d]
    k_transpose_cast<<<dim3(FCr / 64, DD / 64, NE), 256, 0, stream>>>(
        w1 + f0, (size_t)DD * FF, FF, w1t, (size_t)FCr * DD, DD);
    k_mfma<1><<<dim3(FCr / 128, TOK / 128, NE), 256, 0, stream>>>(
        lin_bf, w1t, b1, h_bf, nullptr, cnt, offs, btok, f0,
        DD, DD, FCr, (size_t)FCr * DD, 1, DD);
    // w2[:, f0:f0+FCr, :] -> w2t [e][d][f]
    k_transpose_cast<<<dim3(DD / 64, FCr / 64, NE), 256, 0, stream>>>(
        w2 + (size_t)f0 * DD, (size_t)FF * DD, DD, w2t, (size_t)DD * FCr, FCr);
    k_mfma<2><<<dim3(DD / 128, TOK / 128, NE * nsplit), 256, 0, stream>>>(
        h_bf, w2t, nullptr, nullptr, ob, cnt, offs, btok, f0,
        FCr, FCr, DD, (size_t)DD * FCr, nsplit, FCr / nsplit);
  }

  // pool (+b2) + loss
  k_pool<<<dim3(DD / 256, NB, 8), 256, 0, stream>>>(x, ob, b2, offs, eslot,
                                                    wts, sent);
  k_loss<<<1, 1024, 0, stream>>>(sent, y, out);
}